// Round 4
// baseline (813.653 us; speedup 1.0000x reference)
//
#include <hip/hip_runtime.h>

#define N_NODES 50000
#define N_EDGES 1600000
#define NHEAD 8
#define DH 16
#define D_IN 8
#define E_IN_DIM 12
#define HID 128
#define GRAPHS 64

// ---------------- node pass 1: x = concat(pos, emb[z]);  qk[n,h,j] = scale * sum_d q[n,h,d]*Wk[j,16h+d]
__global__ __launch_bounds__(256) void k_node1(
    const float* __restrict__ pos, const int* __restrict__ z,
    const float* __restrict__ emb,
    const float* __restrict__ Wq, const float* __restrict__ Wk,
    float* __restrict__ x, float* __restrict__ qk)
{
    __shared__ float sWq[D_IN * HID];
    __shared__ float sWk[E_IN_DIM * HID];
    __shared__ float sx[32][D_IN];

    int tid = threadIdx.x;
    for (int i = tid; i < D_IN * HID; i += 256) sWq[i] = Wq[i];
    for (int i = tid; i < E_IN_DIM * HID; i += 256) sWk[i] = Wk[i];

    int nl = tid >> 3;
    int h  = tid & 7;
    int n  = blockIdx.x * 32 + nl;

    if (n < N_NODES) {
        int j = h;
        float v;
        if (j < 3) v = pos[n * 3 + j];
        else       v = emb[z[n] * 5 + (j - 3)];
        sx[nl][j] = v;
        x[n * D_IN + j] = v;
    }
    __syncthreads();
    if (n >= N_NODES) return;

    float q[DH];
    #pragma unroll
    for (int d = 0; d < DH; ++d) {
        float acc = 0.f;
        #pragma unroll
        for (int j = 0; j < D_IN; ++j)
            acc += sx[nl][j] * sWq[j * HID + h * DH + d];
        q[d] = acc;
    }
    const float scale = 0.25f;
    #pragma unroll
    for (int j = 0; j < E_IN_DIM; ++j) {
        float acc = 0.f;
        #pragma unroll
        for (int d = 0; d < DH; ++d)
            acc += q[d] * sWk[j * HID + h * DH + d];
        qk[n * 96 + h * 12 + j] = acc * scale;
    }
}

// ---------------- histogram of dst
__global__ __launch_bounds__(256) void k_hist(
    const int* __restrict__ edge_index, int* __restrict__ counts)
{
    int e = blockIdx.x * 256 + threadIdx.x;
    if (e < N_EDGES) atomicAdd(&counts[edge_index[N_EDGES + e]], 1);
}

// ---------------- exclusive scan over 50K counts (single block)
#define SCAN_T 1024
__global__ __launch_bounds__(1024) void k_scan(
    const int* __restrict__ counts, int* __restrict__ offsets, int* __restrict__ woff)
{
    __shared__ int lsum[SCAN_T];
    int t = threadIdx.x;
    const int CH = (N_NODES + SCAN_T - 1) / SCAN_T;
    int beg = t * CH, end = min(beg + CH, N_NODES);
    int s = 0;
    for (int i = beg; i < end; ++i) s += counts[i];
    lsum[t] = s;
    __syncthreads();
    for (int off = 1; off < SCAN_T; off <<= 1) {
        int v = 0;
        if (t >= off) v = lsum[t - off];
        __syncthreads();
        if (t >= off) lsum[t] += v;
        __syncthreads();
    }
    int pre = (t == 0) ? 0 : lsum[t - 1];
    for (int i = beg; i < end; ++i) {
        offsets[i] = pre; woff[i] = pre;
        pre += counts[i];
    }
    if (t == SCAN_T - 1) offsets[N_NODES] = pre;
}

// ---------------- scatter edges into dst-sorted order: (src, e) pairs
__global__ __launch_bounds__(256) void k_scatter(
    const int* __restrict__ edge_index, int* __restrict__ woff,
    int2* __restrict__ sorted)
{
    int e = blockIdx.x * 256 + threadIdx.x;
    if (e >= N_EDGES) return;
    int src = edge_index[e];
    int dst = edge_index[N_EDGES + e];
    int pos = atomicAdd(&woff[dst], 1);
    sorted[pos] = make_int2(src, e);
}

// ---------------- fused wave-per-node kernel
// Phase A: lane = (es = l>>3, h = l&7); 8 edges in parallel per iteration.
// Phase B: lane owns output dims d = 2l, 2l+1 of feats = agg @ Wo.
__global__ __launch_bounds__(256) void k_nodeE(
    const int* __restrict__ offsets, const int2* __restrict__ sorted,
    const float* __restrict__ x, const float* __restrict__ qk,
    const float* __restrict__ edge_attr,
    const float* __restrict__ Wv, const float* __restrict__ Wo,
    const float* __restrict__ lin_W, const float* __restrict__ lin_b,
    const int* __restrict__ batch,
    float* __restrict__ gsum, float* __restrict__ gcnt)
{
    __shared__ float sWv[E_IN_DIM * HID];   // 1536 floats
    __shared__ float aggl[4][HID];          // one row per wave

    int tid = threadIdx.x;
    for (int i = tid; i < E_IN_DIM * HID; i += 256) sWv[i] = Wv[i];
    __syncthreads();

    int w = tid >> 6;          // wave id in block = local node
    int l = tid & 63;          // lane
    int es = l >> 3;           // edge slot 0..7
    int h  = l & 7;            // head
    int n  = blockIdx.x * 4 + w;
    if (n >= N_NODES) return;

    // load q-vector for this head (48B per h-group, broadcast within group)
    const float4* qr = (const float4*)(qk + n * 96 + h * 12);
    float4 q0 = qr[0], q1 = qr[1], q2 = qr[2];

    int beg = offsets[n], end = offsets[n + 1];

    float sr[12];
    #pragma unroll
    for (int j = 0; j < 12; ++j) sr[j] = 0.f;
    float denom = 0.f;

    #pragma unroll 2
    for (int idx0 = beg; idx0 < end; idx0 += 8) {
        int idx = idx0 + es;
        bool act = idx < end;
        int cidx = act ? idx : beg;            // safe clamped index
        int2 p = sorted[cidx];
        const float4* xp = (const float4*)(x + p.x * 8);
        float4 x0 = xp[0], x1 = xp[1];
        float4 ea = ((const float4*)edge_attr)[p.y];
        float sc = x0.x*q0.x + x0.y*q0.y + x0.z*q0.z + x0.w*q0.w
                 + x1.x*q1.x + x1.y*q1.y + x1.z*q1.z + x1.w*q1.w
                 + ea.x*q2.x + ea.y*q2.y + ea.z*q2.z + ea.w*q2.w;
        float ex = act ? __expf(sc) : 0.f;
        denom += ex;
        sr[0] += ex * x0.x; sr[1]  += ex * x0.y; sr[2]  += ex * x0.z; sr[3]  += ex * x0.w;
        sr[4] += ex * x1.x; sr[5]  += ex * x1.y; sr[6]  += ex * x1.z; sr[7]  += ex * x1.w;
        sr[8] += ex * ea.x; sr[9]  += ex * ea.y; sr[10] += ex * ea.z; sr[11] += ex * ea.w;
    }

    // reduce over the 8 edge-slots (lanes with same h: xor bits 3,4,5)
    #pragma unroll
    for (int m = 8; m <= 32; m <<= 1) {
        denom += __shfl_xor(denom, m);
        #pragma unroll
        for (int j = 0; j < 12; ++j) sr[j] += __shfl_xor(sr[j], m);
    }

    float inv = 1.0f / fmaxf(denom, 1e-9f);

    // @Wv: lane (es,h) computes agg dims d0 = h*16 + 2*es, d1 = d0+1
    {
        int d0 = h * DH + 2 * es;
        float a0 = 0.f, a1 = 0.f;
        #pragma unroll
        for (int j = 0; j < E_IN_DIM; ++j) {
            a0 += sr[j] * sWv[j * HID + d0];
            a1 += sr[j] * sWv[j * HID + d0 + 1];
        }
        float2 av = make_float2(a0 * inv, a1 * inv);
        *(float2*)&aggl[w][d0] = av;
    }
    // no __syncthreads needed: each wave reads only its own aggl row
    __builtin_amdgcn_s_waitcnt(0);  // ensure LDS writes visible to own wave (lgkmcnt 0)

    // Phase B: feats[d] = sum_i agg[i] * Wo[i][d]; lane owns d = 2l, 2l+1
    float f0 = 0.f, f1 = 0.f;
    const float* wop = Wo + (l << 1);
    #pragma unroll 8
    for (int i = 0; i < HID; ++i) {
        float av = aggl[w][i];
        float2 wv = *(const float2*)(wop + i * HID);
        f0 += av * wv.x;
        f1 += av * wv.y;
    }
    float2 lw = *(const float2*)(lin_W + (l << 1));
    float partial = fmaxf(f0, 0.f) * lw.x + fmaxf(f1, 0.f) * lw.y;

    #pragma unroll
    for (int m = 1; m <= 32; m <<= 1)
        partial += __shfl_xor(partial, m);

    if (l == 0) {
        float y = partial + lin_b[0];
        int g = batch[n];
        atomicAdd(&gsum[g], y);
        atomicAdd(&gcnt[g], 1.0f);
    }
}

__global__ void k_final(const float* __restrict__ gsum, const float* __restrict__ gcnt,
                        float* __restrict__ out)
{
    int g = threadIdx.x;
    if (g < GRAPHS) out[g] = gsum[g] / fmaxf(gcnt[g], 1.0f);
}

extern "C" void kernel_launch(void* const* d_in, const int* in_sizes, int n_in,
                              void* d_out, int out_size, void* d_ws, size_t ws_size,
                              hipStream_t stream)
{
    const float* pos       = (const float*)d_in[0];
    const int*   z         = (const int*)  d_in[1];
    const int*   edge_index= (const int*)  d_in[2];
    const float* edge_attr = (const float*)d_in[3];
    const int*   batch     = (const int*)  d_in[4];
    const float* emb       = (const float*)d_in[5];
    const float* Wq        = (const float*)d_in[6];
    const float* Wk        = (const float*)d_in[7];
    const float* Wv        = (const float*)d_in[8];
    const float* Wo        = (const float*)d_in[9];
    const float* lin_W     = (const float*)d_in[10];
    const float* lin_b     = (const float*)d_in[11];
    float* out = (float*)d_out;

    char* ws = (char*)d_ws;
    int*   counts  = (int*)ws;                    // 50000
    float* gsum    = (float*)(counts + N_NODES);  // 64
    float* gcnt    = gsum + GRAPHS;               // 64
    int*   offsets = (int*)(gcnt + GRAPHS);       // 50004
    int*   woff    = offsets + 50004;             // 50000
    int2*  sorted  = (int2*)(woff + N_NODES);     // 1.6M int2 (12.8 MB)
    float* x       = (float*)(sorted + N_EDGES);  // N*8 (1.6 MB)
    float* qk      = x + N_NODES * 8;             // N*96 (19.2 MB)

    hipMemsetAsync(counts, 0, (size_t)(N_NODES + 2 * GRAPHS) * sizeof(int), stream);

    k_node1  <<<(N_NODES + 31) / 32, 256, 0, stream>>>(pos, z, emb, Wq, Wk, x, qk);
    k_hist   <<<(N_EDGES + 255) / 256, 256, 0, stream>>>(edge_index, counts);
    k_scan   <<<1, SCAN_T, 0, stream>>>(counts, offsets, woff);
    k_scatter<<<(N_EDGES + 255) / 256, 256, 0, stream>>>(edge_index, woff, sorted);
    k_nodeE  <<<(N_NODES + 3) / 4, 256, 0, stream>>>(offsets, sorted, x, qk, edge_attr,
                                                     Wv, Wo, lin_W, lin_b, batch, gsum, gcnt);
    k_final  <<<1, 64, 0, stream>>>(gsum, gcnt, out);
}

// Round 5
// 747.447 us; speedup vs baseline: 1.0886x; 1.0886x over previous
//
#include <hip/hip_runtime.h>

#define N_NODES 50000
#define N_EDGES 1600000
#define NHEAD 8
#define DH 16
#define D_IN 8
#define E_IN_DIM 12
#define HID 128
#define GRAPHS 64
#define N_PAD 50016   // nodes rounded up to 32 for k_mlp tile loads

// ---------------- node pass 1: x = concat(pos, emb[z]);  qk[n,h,j] = scale * sum_d q[n,h,d]*Wk[j,16h+d]
__global__ __launch_bounds__(256) void k_node1(
    const float* __restrict__ pos, const int* __restrict__ z,
    const float* __restrict__ emb,
    const float* __restrict__ Wq, const float* __restrict__ Wk,
    float* __restrict__ x, float* __restrict__ qk)
{
    __shared__ float sWq[D_IN * HID];
    __shared__ float sWk[E_IN_DIM * HID];
    __shared__ float sx[32][D_IN];

    int tid = threadIdx.x;
    for (int i = tid; i < D_IN * HID; i += 256) sWq[i] = Wq[i];
    for (int i = tid; i < E_IN_DIM * HID; i += 256) sWk[i] = Wk[i];

    int nl = tid >> 3;
    int h  = tid & 7;
    int n  = blockIdx.x * 32 + nl;

    if (n < N_NODES) {
        int j = h;
        float v;
        if (j < 3) v = pos[n * 3 + j];
        else       v = emb[z[n] * 5 + (j - 3)];
        sx[nl][j] = v;
        x[n * D_IN + j] = v;
    }
    __syncthreads();
    if (n >= N_NODES) return;

    float q[DH];
    #pragma unroll
    for (int d = 0; d < DH; ++d) {
        float acc = 0.f;
        #pragma unroll
        for (int j = 0; j < D_IN; ++j)
            acc += sx[nl][j] * sWq[j * HID + h * DH + d];
        q[d] = acc;
    }
    const float scale = 0.25f;
    #pragma unroll
    for (int j = 0; j < E_IN_DIM; ++j) {
        float acc = 0.f;
        #pragma unroll
        for (int d = 0; d < DH; ++d)
            acc += q[d] * sWk[j * HID + h * DH + d];
        qk[n * 96 + h * 12 + j] = acc * scale;
    }
}

// ---------------- histogram of dst
__global__ __launch_bounds__(256) void k_hist(
    const int* __restrict__ edge_index, int* __restrict__ counts)
{
    int e = blockIdx.x * 256 + threadIdx.x;
    if (e < N_EDGES) atomicAdd(&counts[edge_index[N_EDGES + e]], 1);
}

// ---------------- exclusive scan over 50K counts (single block)
#define SCAN_T 1024
__global__ __launch_bounds__(1024) void k_scan(
    const int* __restrict__ counts, int* __restrict__ offsets, int* __restrict__ woff)
{
    __shared__ int lsum[SCAN_T];
    int t = threadIdx.x;
    const int CH = (N_NODES + SCAN_T - 1) / SCAN_T;
    int beg = t * CH, end = min(beg + CH, N_NODES);
    int s = 0;
    for (int i = beg; i < end; ++i) s += counts[i];
    lsum[t] = s;
    __syncthreads();
    for (int off = 1; off < SCAN_T; off <<= 1) {
        int v = 0;
        if (t >= off) v = lsum[t - off];
        __syncthreads();
        if (t >= off) lsum[t] += v;
        __syncthreads();
    }
    int pre = (t == 0) ? 0 : lsum[t - 1];
    for (int i = beg; i < end; ++i) {
        offsets[i] = pre; woff[i] = pre;
        pre += counts[i];
    }
    if (t == SCAN_T - 1) offsets[N_NODES] = pre;
}

// ---------------- scatter: materialize ein = concat(x[src], edge_attr) into dst-sorted order
__global__ __launch_bounds__(256) void k_scatter_ein(
    const int* __restrict__ edge_index, const float* __restrict__ edge_attr,
    const float* __restrict__ x, int* __restrict__ woff,
    float* __restrict__ sein)
{
    int e = blockIdx.x * 256 + threadIdx.x;
    if (e >= N_EDGES) return;
    int src = edge_index[e];
    int dst = edge_index[N_EDGES + e];
    const float4* xp = (const float4*)(x + src * 8);
    float4 x0 = xp[0], x1 = xp[1];
    float4 ea = ((const float4*)edge_attr)[e];
    int pos = atomicAdd(&woff[dst], 1);
    float4* op = (float4*)(sein + (size_t)pos * 12);
    op[0] = x0; op[1] = x1; op[2] = ea;
}

// ---------------- attention: wave-per-node, purely sequential sein reads
// lane = (es = l>>3, h = l&7). Each lane handles edges es, es+8, ... for head h.
__global__ __launch_bounds__(256) void k_attn(
    const int* __restrict__ offsets, const float* __restrict__ sein,
    const float* __restrict__ qk, const float* __restrict__ Wv,
    float* __restrict__ agg)
{
    __shared__ float sWv[E_IN_DIM * HID];
    int tid = threadIdx.x;
    for (int i = tid; i < E_IN_DIM * HID; i += 256) sWv[i] = Wv[i];
    __syncthreads();

    int w = tid >> 6, l = tid & 63;
    int es = l >> 3, h = l & 7;
    int n = blockIdx.x * 4 + w;
    if (n >= N_NODES) return;

    const float4* qr = (const float4*)(qk + n * 96 + h * 12);
    float4 q0 = qr[0], q1 = qr[1], q2 = qr[2];

    int beg = offsets[n];
    int cnt = offsets[n + 1] - beg;
    const float* base = sein + (size_t)beg * 12;

    float sr[12];
    #pragma unroll
    for (int j = 0; j < 12; ++j) sr[j] = 0.f;
    float denom = 0.f;

    for (int r0 = 0; r0 < cnt; r0 += 32) {
        #pragma unroll
        for (int u = 0; u < 4; ++u) {
            int r = r0 + u * 8 + es;
            bool act = r < cnt;
            int rc = act ? r : (cnt - 1);
            const float4* p = (const float4*)(base + (size_t)rc * 12);
            float4 x0 = p[0], x1 = p[1], ea = p[2];
            float sc = x0.x*q0.x + x0.y*q0.y + x0.z*q0.z + x0.w*q0.w
                     + x1.x*q1.x + x1.y*q1.y + x1.z*q1.z + x1.w*q1.w
                     + ea.x*q2.x + ea.y*q2.y + ea.z*q2.z + ea.w*q2.w;
            float ex = act ? __expf(sc) : 0.f;
            denom += ex;
            sr[0] += ex * x0.x; sr[1]  += ex * x0.y; sr[2]  += ex * x0.z; sr[3]  += ex * x0.w;
            sr[4] += ex * x1.x; sr[5]  += ex * x1.y; sr[6]  += ex * x1.z; sr[7]  += ex * x1.w;
            sr[8] += ex * ea.x; sr[9]  += ex * ea.y; sr[10] += ex * ea.z; sr[11] += ex * ea.w;
        }
    }

    // reduce over edge-slots es (lane bits 3,4,5)
    #pragma unroll
    for (int m = 8; m <= 32; m <<= 1) {
        denom += __shfl_xor(denom, m);
        #pragma unroll
        for (int j = 0; j < 12; ++j) sr[j] += __shfl_xor(sr[j], m);
    }

    float inv = 1.0f / fmaxf(denom, 1e-9f);
    int d0 = h * DH + 2 * es;
    float a0 = 0.f, a1 = 0.f;
    #pragma unroll
    for (int j = 0; j < E_IN_DIM; ++j) {
        a0 += sr[j] * sWv[j * HID + d0];
        a1 += sr[j] * sWv[j * HID + d0 + 1];
    }
    *(float2*)(agg + (size_t)n * HID + d0) = make_float2(a0 * inv, a1 * inv);
}

// ---------------- MLP: LDS-tiled feats = agg@Wo, relu, @lin_W, pool. 32 nodes/block.
// thread -> (h = tid>>5 owns dims [16h,16h+16), nl = tid&31 owns node nl)
__global__ __launch_bounds__(256) void k_mlp(
    const float* __restrict__ agg, const float* __restrict__ Wo,
    const float* __restrict__ lin_W, const float* __restrict__ lin_b,
    const int* __restrict__ batch,
    float* __restrict__ gsum, float* __restrict__ gcnt)
{
    __shared__ float sWo[64 * HID];        // 32 KB: half of Wo (64 input rows)
    __shared__ float sAgg[32][HID + 1];    // stride 129 words: conflict-free nl reads
    __shared__ float sRed[8][33];

    int tid = threadIdx.x;
    int nbase = blockIdx.x * 32;

    // stage agg tile (reads padded region; rows >= N_NODES are garbage, masked later)
    {
        const float4* ag = (const float4*)(agg + (size_t)nbase * HID);
        #pragma unroll
        for (int k = 0; k < 4; ++k) {
            int i4 = k * 256 + tid;            // 0..1023
            float4 v = ag[i4];
            int fi = i4 * 4;
            int r = fi >> 7, c = fi & 127;
            sAgg[r][c] = v.x; sAgg[r][c + 1] = v.y; sAgg[r][c + 2] = v.z; sAgg[r][c + 3] = v.w;
        }
    }

    int h  = tid >> 5;
    int nl = tid & 31;
    int n  = nbase + nl;

    float f[16];
    #pragma unroll
    for (int d = 0; d < 16; ++d) f[d] = 0.f;

    #pragma unroll
    for (int half = 0; half < 2; ++half) {
        __syncthreads();   // protects sWo reuse; first pass also fences sAgg staging
        const float4* wp = (const float4*)(Wo + half * 64 * HID);
        #pragma unroll
        for (int k = 0; k < 8; ++k) {
            int i4 = k * 256 + tid;            // 0..2047
            ((float4*)sWo)[i4] = wp[i4];
        }
        __syncthreads();
        #pragma unroll 4
        for (int i = 0; i < 64; ++i) {
            float av = sAgg[nl][half * 64 + i];
            const float4* wr = (const float4*)(sWo + i * HID + h * 16);
            float4 w0 = wr[0], w1 = wr[1], w2 = wr[2], w3 = wr[3];
            f[0]  += av * w0.x; f[1]  += av * w0.y; f[2]  += av * w0.z; f[3]  += av * w0.w;
            f[4]  += av * w1.x; f[5]  += av * w1.y; f[6]  += av * w1.z; f[7]  += av * w1.w;
            f[8]  += av * w2.x; f[9]  += av * w2.y; f[10] += av * w2.z; f[11] += av * w2.w;
            f[12] += av * w3.x; f[13] += av * w3.y; f[14] += av * w3.z; f[15] += av * w3.w;
        }
    }

    const float4* lwp = (const float4*)(lin_W + h * 16);
    float4 lw0 = lwp[0], lw1 = lwp[1], lw2 = lwp[2], lw3 = lwp[3];
    float ps = fmaxf(f[0],0.f)*lw0.x + fmaxf(f[1],0.f)*lw0.y + fmaxf(f[2],0.f)*lw0.z + fmaxf(f[3],0.f)*lw0.w
             + fmaxf(f[4],0.f)*lw1.x + fmaxf(f[5],0.f)*lw1.y + fmaxf(f[6],0.f)*lw1.z + fmaxf(f[7],0.f)*lw1.w
             + fmaxf(f[8],0.f)*lw2.x + fmaxf(f[9],0.f)*lw2.y + fmaxf(f[10],0.f)*lw2.z + fmaxf(f[11],0.f)*lw2.w
             + fmaxf(f[12],0.f)*lw3.x + fmaxf(f[13],0.f)*lw3.y + fmaxf(f[14],0.f)*lw3.z + fmaxf(f[15],0.f)*lw3.w;

    sRed[h][nl] = ps;
    __syncthreads();
    if (h == 0 && n < N_NODES) {
        float y = lin_b[0];
        #pragma unroll
        for (int k = 0; k < 8; ++k) y += sRed[k][nl];
        int g = batch[n];
        atomicAdd(&gsum[g], y);
        atomicAdd(&gcnt[g], 1.0f);
    }
}

// ================= fallback path (round-4, used only if workspace too small) =================
__global__ __launch_bounds__(256) void k_scatter(
    const int* __restrict__ edge_index, int* __restrict__ woff,
    int2* __restrict__ sorted)
{
    int e = blockIdx.x * 256 + threadIdx.x;
    if (e >= N_EDGES) return;
    int src = edge_index[e];
    int dst = edge_index[N_EDGES + e];
    int pos = atomicAdd(&woff[dst], 1);
    sorted[pos] = make_int2(src, e);
}

__global__ __launch_bounds__(256) void k_nodeE(
    const int* __restrict__ offsets, const int2* __restrict__ sorted,
    const float* __restrict__ x, const float* __restrict__ qk,
    const float* __restrict__ edge_attr,
    const float* __restrict__ Wv, const float* __restrict__ Wo,
    const float* __restrict__ lin_W, const float* __restrict__ lin_b,
    const int* __restrict__ batch,
    float* __restrict__ gsum, float* __restrict__ gcnt)
{
    __shared__ float sWv[E_IN_DIM * HID];
    __shared__ float aggl[4][HID];

    int tid = threadIdx.x;
    for (int i = tid; i < E_IN_DIM * HID; i += 256) sWv[i] = Wv[i];
    __syncthreads();

    int w = tid >> 6;
    int l = tid & 63;
    int es = l >> 3;
    int h  = l & 7;
    int n  = blockIdx.x * 4 + w;
    if (n >= N_NODES) return;

    const float4* qr = (const float4*)(qk + n * 96 + h * 12);
    float4 q0 = qr[0], q1 = qr[1], q2 = qr[2];

    int beg = offsets[n], end = offsets[n + 1];
    float sr[12];
    #pragma unroll
    for (int j = 0; j < 12; ++j) sr[j] = 0.f;
    float denom = 0.f;

    #pragma unroll 2
    for (int idx0 = beg; idx0 < end; idx0 += 8) {
        int idx = idx0 + es;
        bool act = idx < end;
        int cidx = act ? idx : beg;
        int2 p = sorted[cidx];
        const float4* xp = (const float4*)(x + p.x * 8);
        float4 x0 = xp[0], x1 = xp[1];
        float4 ea = ((const float4*)edge_attr)[p.y];
        float sc = x0.x*q0.x + x0.y*q0.y + x0.z*q0.z + x0.w*q0.w
                 + x1.x*q1.x + x1.y*q1.y + x1.z*q1.z + x1.w*q1.w
                 + ea.x*q2.x + ea.y*q2.y + ea.z*q2.z + ea.w*q2.w;
        float ex = act ? __expf(sc) : 0.f;
        denom += ex;
        sr[0] += ex * x0.x; sr[1]  += ex * x0.y; sr[2]  += ex * x0.z; sr[3]  += ex * x0.w;
        sr[4] += ex * x1.x; sr[5]  += ex * x1.y; sr[6]  += ex * x1.z; sr[7]  += ex * x1.w;
        sr[8] += ex * ea.x; sr[9]  += ex * ea.y; sr[10] += ex * ea.z; sr[11] += ex * ea.w;
    }

    #pragma unroll
    for (int m = 8; m <= 32; m <<= 1) {
        denom += __shfl_xor(denom, m);
        #pragma unroll
        for (int j = 0; j < 12; ++j) sr[j] += __shfl_xor(sr[j], m);
    }

    float inv = 1.0f / fmaxf(denom, 1e-9f);
    {
        int d0 = h * DH + 2 * es;
        float a0 = 0.f, a1 = 0.f;
        #pragma unroll
        for (int j = 0; j < E_IN_DIM; ++j) {
            a0 += sr[j] * sWv[j * HID + d0];
            a1 += sr[j] * sWv[j * HID + d0 + 1];
        }
        *(float2*)&aggl[w][d0] = make_float2(a0 * inv, a1 * inv);
    }
    __builtin_amdgcn_s_waitcnt(0);

    float f0 = 0.f, f1 = 0.f;
    const float* wop = Wo + (l << 1);
    #pragma unroll 8
    for (int i = 0; i < HID; ++i) {
        float av = aggl[w][i];
        float2 wv = *(const float2*)(wop + i * HID);
        f0 += av * wv.x;
        f1 += av * wv.y;
    }
    float2 lw = *(const float2*)(lin_W + (l << 1));
    float partial = fmaxf(f0, 0.f) * lw.x + fmaxf(f1, 0.f) * lw.y;

    #pragma unroll
    for (int m = 1; m <= 32; m <<= 1)
        partial += __shfl_xor(partial, m);

    if (l == 0) {
        float y = partial + lin_b[0];
        int g = batch[n];
        atomicAdd(&gsum[g], y);
        atomicAdd(&gcnt[g], 1.0f);
    }
}

__global__ void k_final(const float* __restrict__ gsum, const float* __restrict__ gcnt,
                        float* __restrict__ out)
{
    int g = threadIdx.x;
    if (g < GRAPHS) out[g] = gsum[g] / fmaxf(gcnt[g], 1.0f);
}

extern "C" void kernel_launch(void* const* d_in, const int* in_sizes, int n_in,
                              void* d_out, int out_size, void* d_ws, size_t ws_size,
                              hipStream_t stream)
{
    const float* pos       = (const float*)d_in[0];
    const int*   z         = (const int*)  d_in[1];
    const int*   edge_index= (const int*)  d_in[2];
    const float* edge_attr = (const float*)d_in[3];
    const int*   batch     = (const int*)  d_in[4];
    const float* emb       = (const float*)d_in[5];
    const float* Wq        = (const float*)d_in[6];
    const float* Wk        = (const float*)d_in[7];
    const float* Wv        = (const float*)d_in[8];
    const float* Wo        = (const float*)d_in[9];
    const float* lin_W     = (const float*)d_in[10];
    const float* lin_b     = (const float*)d_in[11];
    float* out = (float*)d_out;

    char* ws = (char*)d_ws;
    int*   counts  = (int*)ws;                    // 50000
    float* gsum    = (float*)(counts + N_NODES);  // 64
    float* gcnt    = gsum + GRAPHS;               // 64
    int*   offsets = (int*)(gcnt + GRAPHS);       // 50004
    int*   woff    = offsets + 50004;             // 50000
    char*  tail    = (char*)(woff + N_NODES);
    size_t fixed   = (size_t)(tail - ws);

    size_t need_main = fixed + (size_t)N_EDGES * 48          // sein
                     + (size_t)N_NODES * 32                  // x
                     + (size_t)N_NODES * 384                 // qk
                     + (size_t)N_PAD   * 512;                // agg (padded)

    hipMemsetAsync(counts, 0, (size_t)(N_NODES + 2 * GRAPHS) * sizeof(int), stream);

    if (ws_size >= need_main) {
        float* sein = (float*)tail;
        float* x    = sein + (size_t)N_EDGES * 12;
        float* qk   = x + (size_t)N_NODES * 8;
        float* agg  = qk + (size_t)N_NODES * 96;

        k_node1      <<<(N_NODES + 31) / 32, 256, 0, stream>>>(pos, z, emb, Wq, Wk, x, qk);
        k_hist       <<<(N_EDGES + 255) / 256, 256, 0, stream>>>(edge_index, counts);
        k_scan       <<<1, SCAN_T, 0, stream>>>(counts, offsets, woff);
        k_scatter_ein<<<(N_EDGES + 255) / 256, 256, 0, stream>>>(edge_index, edge_attr, x, woff, sein);
        k_attn       <<<(N_NODES + 3) / 4, 256, 0, stream>>>(offsets, sein, qk, Wv, agg);
        k_mlp        <<<(N_PAD / 32), 256, 0, stream>>>(agg, Wo, lin_W, lin_b, batch, gsum, gcnt);
    } else {
        int2*  sorted = (int2*)tail;
        float* x      = (float*)(sorted + N_EDGES);
        float* qk     = x + N_NODES * 8;

        k_node1  <<<(N_NODES + 31) / 32, 256, 0, stream>>>(pos, z, emb, Wq, Wk, x, qk);
        k_hist   <<<(N_EDGES + 255) / 256, 256, 0, stream>>>(edge_index, counts);
        k_scan   <<<1, SCAN_T, 0, stream>>>(counts, offsets, woff);
        k_scatter<<<(N_EDGES + 255) / 256, 256, 0, stream>>>(edge_index, woff, sorted);
        k_nodeE  <<<(N_NODES + 3) / 4, 256, 0, stream>>>(offsets, sorted, x, qk, edge_attr,
                                                         Wv, Wo, lin_W, lin_b, batch, gsum, gcnt);
    }
    k_final<<<1, 64, 0, stream>>>(gsum, gcnt, out);
}

// Round 6
// 397.063 us; speedup vs baseline: 2.0492x; 1.8824x over previous
//
#include <hip/hip_runtime.h>

#define N_NODES 50000
#define N_EDGES 1600000
#define NHEAD 8
#define DH 16
#define D_IN 8
#define E_IN_DIM 12
#define HID 128
#define GRAPHS 64
#define N_PAD 50016   // nodes rounded up to 32 for k_mlp tile loads

// ---------------- node pass 1: x = concat(pos, emb[z]);  qk[n,h,j] = scale * sum_d q[n,h,d]*Wk[j,16h+d]
__global__ __launch_bounds__(256) void k_node1(
    const float* __restrict__ pos, const int* __restrict__ z,
    const float* __restrict__ emb,
    const float* __restrict__ Wq, const float* __restrict__ Wk,
    float* __restrict__ x, float* __restrict__ qk)
{
    __shared__ float sWq[D_IN * HID];
    __shared__ float sWk[E_IN_DIM * HID];
    __shared__ float sx[32][D_IN];

    int tid = threadIdx.x;
    for (int i = tid; i < D_IN * HID; i += 256) sWq[i] = Wq[i];
    for (int i = tid; i < E_IN_DIM * HID; i += 256) sWk[i] = Wk[i];

    int nl = tid >> 3;
    int h  = tid & 7;
    int n  = blockIdx.x * 32 + nl;

    if (n < N_NODES) {
        int j = h;
        float v;
        if (j < 3) v = pos[n * 3 + j];
        else       v = emb[z[n] * 5 + (j - 3)];
        sx[nl][j] = v;
        x[n * D_IN + j] = v;
    }
    __syncthreads();
    if (n >= N_NODES) return;

    float q[DH];
    #pragma unroll
    for (int d = 0; d < DH; ++d) {
        float acc = 0.f;
        #pragma unroll
        for (int j = 0; j < D_IN; ++j)
            acc += sx[nl][j] * sWq[j * HID + h * DH + d];
        q[d] = acc;
    }
    const float scale = 0.25f;
    #pragma unroll
    for (int j = 0; j < E_IN_DIM; ++j) {
        float acc = 0.f;
        #pragma unroll
        for (int d = 0; d < DH; ++d)
            acc += q[d] * sWk[j * HID + h * DH + d];
        qk[n * 96 + h * 12 + j] = acc * scale;
    }
}

// ---------------- histogram of dst
__global__ __launch_bounds__(256) void k_hist(
    const int* __restrict__ edge_index, int* __restrict__ counts)
{
    int e = blockIdx.x * 256 + threadIdx.x;
    if (e < N_EDGES) atomicAdd(&counts[edge_index[N_EDGES + e]], 1);
}

// ---------------- exclusive scan over 50K counts (single block)
#define SCAN_T 1024
__global__ __launch_bounds__(1024) void k_scan(
    const int* __restrict__ counts, int* __restrict__ offsets, int* __restrict__ woff)
{
    __shared__ int lsum[SCAN_T];
    int t = threadIdx.x;
    const int CH = (N_NODES + SCAN_T - 1) / SCAN_T;
    int beg = t * CH, end = min(beg + CH, N_NODES);
    int s = 0;
    for (int i = beg; i < end; ++i) s += counts[i];
    lsum[t] = s;
    __syncthreads();
    for (int off = 1; off < SCAN_T; off <<= 1) {
        int v = 0;
        if (t >= off) v = lsum[t - off];
        __syncthreads();
        if (t >= off) lsum[t] += v;
        __syncthreads();
    }
    int pre = (t == 0) ? 0 : lsum[t - 1];
    for (int i = beg; i < end; ++i) {
        offsets[i] = pre; woff[i] = pre;
        pre += counts[i];
    }
    if (t == SCAN_T - 1) offsets[N_NODES] = pre;
}

// ---------------- scatter: materialize ein = concat(x[src], edge_attr) into dst-sorted order
__global__ __launch_bounds__(256) void k_scatter_ein(
    const int* __restrict__ edge_index, const float* __restrict__ edge_attr,
    const float* __restrict__ x, int* __restrict__ woff,
    float* __restrict__ sein)
{
    int e = blockIdx.x * 256 + threadIdx.x;
    if (e >= N_EDGES) return;
    int src = edge_index[e];
    int dst = edge_index[N_EDGES + e];
    const float4* xp = (const float4*)(x + src * 8);
    float4 x0 = xp[0], x1 = xp[1];
    float4 ea = ((const float4*)edge_attr)[e];
    int pos = atomicAdd(&woff[dst], 1);
    float4* op = (float4*)(sein + (size_t)pos * 12);
    op[0] = x0; op[1] = x1; op[2] = ea;
}

// ---------------- attention: wave-per-node, purely sequential sein reads
__global__ __launch_bounds__(256) void k_attn(
    const int* __restrict__ offsets, const float* __restrict__ sein,
    const float* __restrict__ qk, const float* __restrict__ Wv,
    float* __restrict__ agg)
{
    __shared__ float sWv[E_IN_DIM * HID];
    int tid = threadIdx.x;
    for (int i = tid; i < E_IN_DIM * HID; i += 256) sWv[i] = Wv[i];
    __syncthreads();

    int w = tid >> 6, l = tid & 63;
    int es = l >> 3, h = l & 7;
    int n = blockIdx.x * 4 + w;
    if (n >= N_NODES) return;

    const float4* qr = (const float4*)(qk + n * 96 + h * 12);
    float4 q0 = qr[0], q1 = qr[1], q2 = qr[2];

    int beg = offsets[n];
    int cnt = offsets[n + 1] - beg;
    const float* base = sein + (size_t)beg * 12;

    float sr[12];
    #pragma unroll
    for (int j = 0; j < 12; ++j) sr[j] = 0.f;
    float denom = 0.f;

    for (int r0 = 0; r0 < cnt; r0 += 32) {
        #pragma unroll
        for (int u = 0; u < 4; ++u) {
            int r = r0 + u * 8 + es;
            bool act = r < cnt;
            int rc = act ? r : (cnt - 1);
            const float4* p = (const float4*)(base + (size_t)rc * 12);
            float4 x0 = p[0], x1 = p[1], ea = p[2];
            float sc = x0.x*q0.x + x0.y*q0.y + x0.z*q0.z + x0.w*q0.w
                     + x1.x*q1.x + x1.y*q1.y + x1.z*q1.z + x1.w*q1.w
                     + ea.x*q2.x + ea.y*q2.y + ea.z*q2.z + ea.w*q2.w;
            float ex = act ? __expf(sc) : 0.f;
            denom += ex;
            sr[0] += ex * x0.x; sr[1]  += ex * x0.y; sr[2]  += ex * x0.z; sr[3]  += ex * x0.w;
            sr[4] += ex * x1.x; sr[5]  += ex * x1.y; sr[6]  += ex * x1.z; sr[7]  += ex * x1.w;
            sr[8] += ex * ea.x; sr[9]  += ex * ea.y; sr[10] += ex * ea.z; sr[11] += ex * ea.w;
        }
    }

    #pragma unroll
    for (int m = 8; m <= 32; m <<= 1) {
        denom += __shfl_xor(denom, m);
        #pragma unroll
        for (int j = 0; j < 12; ++j) sr[j] += __shfl_xor(sr[j], m);
    }

    float inv = 1.0f / fmaxf(denom, 1e-9f);
    int d0 = h * DH + 2 * es;
    float a0 = 0.f, a1 = 0.f;
    #pragma unroll
    for (int j = 0; j < E_IN_DIM; ++j) {
        a0 += sr[j] * sWv[j * HID + d0];
        a1 += sr[j] * sWv[j * HID + d0 + 1];
    }
    *(float2*)(agg + (size_t)n * HID + d0) = make_float2(a0 * inv, a1 * inv);
}

// ---------------- MLP: LDS-tiled feats = agg@Wo, relu, @lin_W, pool (LDS-bucketed atomics).
__global__ __launch_bounds__(256) void k_mlp(
    const float* __restrict__ agg, const float* __restrict__ Wo,
    const float* __restrict__ lin_W, const float* __restrict__ lin_b,
    const int* __restrict__ batch,
    float* __restrict__ gsum, float* __restrict__ gcnt)
{
    __shared__ float sWo[64 * HID];        // 32 KB: half of Wo (64 input rows)
    __shared__ float sAgg[32][HID + 1];    // stride 129 words: conflict-free nl reads
    __shared__ float sRed[8][33];
    __shared__ float bsum[GRAPHS];         // per-block graph buckets
    __shared__ int   bcnt[GRAPHS];

    int tid = threadIdx.x;
    int nbase = blockIdx.x * 32;

    if (tid < GRAPHS) { bsum[tid] = 0.f; bcnt[tid] = 0; }

    // stage agg tile (padded region; rows >= N_NODES are garbage, masked later)
    {
        const float4* ag = (const float4*)(agg + (size_t)nbase * HID);
        #pragma unroll
        for (int k = 0; k < 4; ++k) {
            int i4 = k * 256 + tid;            // 0..1023
            float4 v = ag[i4];
            int fi = i4 * 4;
            int r = fi >> 7, c = fi & 127;
            sAgg[r][c] = v.x; sAgg[r][c + 1] = v.y; sAgg[r][c + 2] = v.z; sAgg[r][c + 3] = v.w;
        }
    }

    int h  = tid >> 5;
    int nl = tid & 31;
    int n  = nbase + nl;

    float f[16];
    #pragma unroll
    for (int d = 0; d < 16; ++d) f[d] = 0.f;

    #pragma unroll
    for (int half = 0; half < 2; ++half) {
        __syncthreads();   // protects sWo reuse; first pass also fences sAgg staging + bucket init
        const float4* wp = (const float4*)(Wo + half * 64 * HID);
        #pragma unroll
        for (int k = 0; k < 8; ++k) {
            int i4 = k * 256 + tid;            // 0..2047
            ((float4*)sWo)[i4] = wp[i4];
        }
        __syncthreads();
        #pragma unroll 4
        for (int i = 0; i < 64; ++i) {
            float av = sAgg[nl][half * 64 + i];
            const float4* wr = (const float4*)(sWo + i * HID + h * 16);
            float4 w0 = wr[0], w1 = wr[1], w2 = wr[2], w3 = wr[3];
            f[0]  += av * w0.x; f[1]  += av * w0.y; f[2]  += av * w0.z; f[3]  += av * w0.w;
            f[4]  += av * w1.x; f[5]  += av * w1.y; f[6]  += av * w1.z; f[7]  += av * w1.w;
            f[8]  += av * w2.x; f[9]  += av * w2.y; f[10] += av * w2.z; f[11] += av * w2.w;
            f[12] += av * w3.x; f[13] += av * w3.y; f[14] += av * w3.z; f[15] += av * w3.w;
        }
    }

    const float4* lwp = (const float4*)(lin_W + h * 16);
    float4 lw0 = lwp[0], lw1 = lwp[1], lw2 = lwp[2], lw3 = lwp[3];
    float ps = fmaxf(f[0],0.f)*lw0.x + fmaxf(f[1],0.f)*lw0.y + fmaxf(f[2],0.f)*lw0.z + fmaxf(f[3],0.f)*lw0.w
             + fmaxf(f[4],0.f)*lw1.x + fmaxf(f[5],0.f)*lw1.y + fmaxf(f[6],0.f)*lw1.z + fmaxf(f[7],0.f)*lw1.w
             + fmaxf(f[8],0.f)*lw2.x + fmaxf(f[9],0.f)*lw2.y + fmaxf(f[10],0.f)*lw2.z + fmaxf(f[11],0.f)*lw2.w
             + fmaxf(f[12],0.f)*lw3.x + fmaxf(f[13],0.f)*lw3.y + fmaxf(f[14],0.f)*lw3.z + fmaxf(f[15],0.f)*lw3.w;

    sRed[h][nl] = ps;
    __syncthreads();
    if (h == 0 && n < N_NODES) {
        float y = lin_b[0];
        #pragma unroll
        for (int k = 0; k < 8; ++k) y += sRed[k][nl];
        int g = batch[n];
        atomicAdd(&bsum[g], y);   // LDS atomic: cheap, <=32-way
        atomicAdd(&bcnt[g], 1);
    }
    __syncthreads();
    if (tid < GRAPHS) {
        int c = bcnt[tid];
        if (c > 0) {
            atomicAdd(&gsum[tid], bsum[tid]);        // ~1-2 global atomics per block
            atomicAdd(&gcnt[tid], (float)c);
        }
    }
}

// ================= fallback path (used only if workspace too small) =================
__global__ __launch_bounds__(256) void k_scatter(
    const int* __restrict__ edge_index, int* __restrict__ woff,
    int2* __restrict__ sorted)
{
    int e = blockIdx.x * 256 + threadIdx.x;
    if (e >= N_EDGES) return;
    int src = edge_index[e];
    int dst = edge_index[N_EDGES + e];
    int pos = atomicAdd(&woff[dst], 1);
    sorted[pos] = make_int2(src, e);
}

__global__ __launch_bounds__(256) void k_nodeE(
    const int* __restrict__ offsets, const int2* __restrict__ sorted,
    const float* __restrict__ x, const float* __restrict__ qk,
    const float* __restrict__ edge_attr,
    const float* __restrict__ Wv, const float* __restrict__ Wo,
    const float* __restrict__ lin_W, const float* __restrict__ lin_b,
    const int* __restrict__ batch,
    float* __restrict__ gsum, float* __restrict__ gcnt)
{
    __shared__ float sWv[E_IN_DIM * HID];
    __shared__ float aggl[4][HID];

    int tid = threadIdx.x;
    for (int i = tid; i < E_IN_DIM * HID; i += 256) sWv[i] = Wv[i];
    __syncthreads();

    int w = tid >> 6;
    int l = tid & 63;
    int es = l >> 3;
    int h  = l & 7;
    int n  = blockIdx.x * 4 + w;
    if (n >= N_NODES) return;

    const float4* qr = (const float4*)(qk + n * 96 + h * 12);
    float4 q0 = qr[0], q1 = qr[1], q2 = qr[2];

    int beg = offsets[n], end = offsets[n + 1];
    float sr[12];
    #pragma unroll
    for (int j = 0; j < 12; ++j) sr[j] = 0.f;
    float denom = 0.f;

    #pragma unroll 2
    for (int idx0 = beg; idx0 < end; idx0 += 8) {
        int idx = idx0 + es;
        bool act = idx < end;
        int cidx = act ? idx : beg;
        int2 p = sorted[cidx];
        const float4* xp = (const float4*)(x + p.x * 8);
        float4 x0 = xp[0], x1 = xp[1];
        float4 ea = ((const float4*)edge_attr)[p.y];
        float sc = x0.x*q0.x + x0.y*q0.y + x0.z*q0.z + x0.w*q0.w
                 + x1.x*q1.x + x1.y*q1.y + x1.z*q1.z + x1.w*q1.w
                 + ea.x*q2.x + ea.y*q2.y + ea.z*q2.z + ea.w*q2.w;
        float ex = act ? __expf(sc) : 0.f;
        denom += ex;
        sr[0] += ex * x0.x; sr[1]  += ex * x0.y; sr[2]  += ex * x0.z; sr[3]  += ex * x0.w;
        sr[4] += ex * x1.x; sr[5]  += ex * x1.y; sr[6]  += ex * x1.z; sr[7]  += ex * x1.w;
        sr[8] += ex * ea.x; sr[9]  += ex * ea.y; sr[10] += ex * ea.z; sr[11] += ex * ea.w;
    }

    #pragma unroll
    for (int m = 8; m <= 32; m <<= 1) {
        denom += __shfl_xor(denom, m);
        #pragma unroll
        for (int j = 0; j < 12; ++j) sr[j] += __shfl_xor(sr[j], m);
    }

    float inv = 1.0f / fmaxf(denom, 1e-9f);
    {
        int d0 = h * DH + 2 * es;
        float a0 = 0.f, a1 = 0.f;
        #pragma unroll
        for (int j = 0; j < E_IN_DIM; ++j) {
            a0 += sr[j] * sWv[j * HID + d0];
            a1 += sr[j] * sWv[j * HID + d0 + 1];
        }
        *(float2*)&aggl[w][d0] = make_float2(a0 * inv, a1 * inv);
    }
    __builtin_amdgcn_s_waitcnt(0);

    float f0 = 0.f, f1 = 0.f;
    const float* wop = Wo + (l << 1);
    #pragma unroll 8
    for (int i = 0; i < HID; ++i) {
        float av = aggl[w][i];
        float2 wv = *(const float2*)(wop + i * HID);
        f0 += av * wv.x;
        f1 += av * wv.y;
    }
    float2 lw = *(const float2*)(lin_W + (l << 1));
    float partial = fmaxf(f0, 0.f) * lw.x + fmaxf(f1, 0.f) * lw.y;

    #pragma unroll
    for (int m = 1; m <= 32; m <<= 1)
        partial += __shfl_xor(partial, m);

    if (l == 0) {
        float y = partial + lin_b[0];
        int g = batch[n];
        atomicAdd(&gsum[g], y);
        atomicAdd(&gcnt[g], 1.0f);
    }
}

__global__ void k_final(const float* __restrict__ gsum, const float* __restrict__ gcnt,
                        float* __restrict__ out)
{
    int g = threadIdx.x;
    if (g < GRAPHS) out[g] = gsum[g] / fmaxf(gcnt[g], 1.0f);
}

extern "C" void kernel_launch(void* const* d_in, const int* in_sizes, int n_in,
                              void* d_out, int out_size, void* d_ws, size_t ws_size,
                              hipStream_t stream)
{
    const float* pos       = (const float*)d_in[0];
    const int*   z         = (const int*)  d_in[1];
    const int*   edge_index= (const int*)  d_in[2];
    const float* edge_attr = (const float*)d_in[3];
    const int*   batch     = (const int*)  d_in[4];
    const float* emb       = (const float*)d_in[5];
    const float* Wq        = (const float*)d_in[6];
    const float* Wk        = (const float*)d_in[7];
    const float* Wv        = (const float*)d_in[8];
    const float* Wo        = (const float*)d_in[9];
    const float* lin_W     = (const float*)d_in[10];
    const float* lin_b     = (const float*)d_in[11];
    float* out = (float*)d_out;

    char* ws = (char*)d_ws;
    int*   counts  = (int*)ws;                    // 50000
    float* gsum    = (float*)(counts + N_NODES);  // 64
    float* gcnt    = gsum + GRAPHS;               // 64
    int*   offsets = (int*)(gcnt + GRAPHS);       // 50004
    int*   woff    = offsets + 50004;             // 50000
    char*  tail    = (char*)(woff + N_NODES);
    size_t fixed   = (size_t)(tail - ws);

    size_t need_main = fixed + (size_t)N_EDGES * 48          // sein
                     + (size_t)N_NODES * 32                  // x
                     + (size_t)N_NODES * 384                 // qk
                     + (size_t)N_PAD   * 512;                // agg (padded)

    hipMemsetAsync(counts, 0, (size_t)(N_NODES + 2 * GRAPHS) * sizeof(int), stream);

    if (ws_size >= need_main) {
        float* sein = (float*)tail;
        float* x    = sein + (size_t)N_EDGES * 12;
        float* qk   = x + (size_t)N_NODES * 8;
        float* agg  = qk + (size_t)N_NODES * 96;

        k_node1      <<<(N_NODES + 31) / 32, 256, 0, stream>>>(pos, z, emb, Wq, Wk, x, qk);
        k_hist       <<<(N_EDGES + 255) / 256, 256, 0, stream>>>(edge_index, counts);
        k_scan       <<<1, SCAN_T, 0, stream>>>(counts, offsets, woff);
        k_scatter_ein<<<(N_EDGES + 255) / 256, 256, 0, stream>>>(edge_index, edge_attr, x, woff, sein);
        k_attn       <<<(N_NODES + 3) / 4, 256, 0, stream>>>(offsets, sein, qk, Wv, agg);
        k_mlp        <<<(N_PAD / 32), 256, 0, stream>>>(agg, Wo, lin_W, lin_b, batch, gsum, gcnt);
    } else {
        int2*  sorted = (int2*)tail;
        float* x      = (float*)(sorted + N_EDGES);
        float* qk     = x + N_NODES * 8;

        k_node1  <<<(N_NODES + 31) / 32, 256, 0, stream>>>(pos, z, emb, Wq, Wk, x, qk);
        k_hist   <<<(N_EDGES + 255) / 256, 256, 0, stream>>>(edge_index, counts);
        k_scan   <<<1, SCAN_T, 0, stream>>>(counts, offsets, woff);
        k_scatter<<<(N_EDGES + 255) / 256, 256, 0, stream>>>(edge_index, woff, sorted);
        k_nodeE  <<<(N_NODES + 3) / 4, 256, 0, stream>>>(offsets, sorted, x, qk, edge_attr,
                                                         Wv, Wo, lin_W, lin_b, batch, gsum, gcnt);
    }
    k_final<<<1, 64, 0, stream>>>(gsum, gcnt, out);
}

// Round 7
// 296.917 us; speedup vs baseline: 2.7403x; 1.3373x over previous
//
#include <hip/hip_runtime.h>

#define N_NODES 50000
#define N_EDGES 1600000
#define NHEAD 8
#define DH 16
#define D_IN 8
#define E_IN_DIM 12
#define HID 128
#define GRAPHS 64
#define N_PAD 50016   // nodes rounded up to 32 for k_mlp tile loads
#define NSCB ((N_NODES + 255) / 256)   // 196 scan blocks

// ---------------- node pass 1: x = concat(pos, emb[z]);  qk[n,h,j] = scale * sum_d q[n,h,d]*Wk[j,16h+d]
__global__ __launch_bounds__(256) void k_node1(
    const float* __restrict__ pos, const int* __restrict__ z,
    const float* __restrict__ emb,
    const float* __restrict__ Wq, const float* __restrict__ Wk,
    float* __restrict__ x, float* __restrict__ qk)
{
    __shared__ float sWq[D_IN * HID];
    __shared__ float sWk[E_IN_DIM * HID];
    __shared__ float sx[32][D_IN];

    int tid = threadIdx.x;
    for (int i = tid; i < D_IN * HID; i += 256) sWq[i] = Wq[i];
    for (int i = tid; i < E_IN_DIM * HID; i += 256) sWk[i] = Wk[i];

    int nl = tid >> 3;
    int h  = tid & 7;
    int n  = blockIdx.x * 32 + nl;

    if (n < N_NODES) {
        int j = h;
        float v;
        if (j < 3) v = pos[n * 3 + j];
        else       v = emb[z[n] * 5 + (j - 3)];
        sx[nl][j] = v;
        x[n * D_IN + j] = v;
    }
    __syncthreads();
    if (n >= N_NODES) return;

    float q[DH];
    #pragma unroll
    for (int d = 0; d < DH; ++d) {
        float acc = 0.f;
        #pragma unroll
        for (int j = 0; j < D_IN; ++j)
            acc += sx[nl][j] * sWq[j * HID + h * DH + d];
        q[d] = acc;
    }
    const float scale = 0.25f;
    #pragma unroll
    for (int j = 0; j < E_IN_DIM; ++j) {
        float acc = 0.f;
        #pragma unroll
        for (int d = 0; d < DH; ++d)
            acc += q[d] * sWk[j * HID + h * DH + d];
        qk[n * 96 + h * 12 + j] = acc * scale;
    }
}

// ---------------- histogram of dst (int4-vectorized: 4 edges/thread)
__global__ __launch_bounds__(256) void k_hist(
    const int* __restrict__ edge_index, int* __restrict__ counts)
{
    int t = blockIdx.x * 256 + threadIdx.x;
    if (t * 4 >= N_EDGES) return;
    int4 d4 = ((const int4*)(edge_index + N_EDGES))[t];
    atomicAdd(&counts[d4.x], 1);
    atomicAdd(&counts[d4.y], 1);
    atomicAdd(&counts[d4.z], 1);
    atomicAdd(&counts[d4.w], 1);
}

// ---------------- decoupled 3-phase exclusive scan over 50K counts
__global__ __launch_bounds__(256) void k_scan1(
    const int* __restrict__ counts, int* __restrict__ offsets, int* __restrict__ bsum)
{
    __shared__ int tmp[256];
    int b = blockIdx.x, t = threadIdx.x;
    int i = b * 256 + t;
    int v = (i < N_NODES) ? counts[i] : 0;
    tmp[t] = v;
    __syncthreads();
    #pragma unroll
    for (int off = 1; off < 256; off <<= 1) {
        int u = (t >= off) ? tmp[t - off] : 0;
        __syncthreads();
        if (t >= off) tmp[t] += u;
        __syncthreads();
    }
    if (i < N_NODES) offsets[i] = tmp[t] - v;   // block-local exclusive
    if (t == 255) bsum[b] = tmp[255];           // block total
}

__global__ __launch_bounds__(256) void k_scan2(
    const int* __restrict__ bsum, int* __restrict__ bbase, int* __restrict__ offsets)
{
    __shared__ int tmp[256];
    int t = threadIdx.x;
    int v = (t < NSCB) ? bsum[t] : 0;
    tmp[t] = v;
    __syncthreads();
    #pragma unroll
    for (int off = 1; off < 256; off <<= 1) {
        int u = (t >= off) ? tmp[t - off] : 0;
        __syncthreads();
        if (t >= off) tmp[t] += u;
        __syncthreads();
    }
    if (t < NSCB) bbase[t] = tmp[t] - v;        // exclusive base per block
    if (t == 255) offsets[N_NODES] = tmp[255];  // grand total == N_EDGES
}

__global__ __launch_bounds__(256) void k_scan3(
    int* __restrict__ offsets, int* __restrict__ woff, const int* __restrict__ bbase)
{
    int b = blockIdx.x, t = threadIdx.x;
    int i = b * 256 + t;
    if (i < N_NODES) {
        int o = offsets[i] + bbase[b];
        offsets[i] = o;
        woff[i] = o;
    }
}

// ---------------- scatter: materialize ein = concat(x[src], edge_attr) into dst-sorted order
__global__ __launch_bounds__(256) void k_scatter_ein(
    const int* __restrict__ edge_index, const float* __restrict__ edge_attr,
    const float* __restrict__ x, int* __restrict__ woff,
    float* __restrict__ sein)
{
    int e = blockIdx.x * 256 + threadIdx.x;
    if (e >= N_EDGES) return;
    int src = edge_index[e];
    int dst = edge_index[N_EDGES + e];
    const float4* xp = (const float4*)(x + src * 8);
    float4 x0 = xp[0], x1 = xp[1];
    float4 ea = ((const float4*)edge_attr)[e];
    int pos = atomicAdd(&woff[dst], 1);
    float4* op = (float4*)(sein + (size_t)pos * 12);
    op[0] = x0; op[1] = x1; op[2] = ea;
}

// ---------------- attention: wave-per-node, purely sequential sein reads
__global__ __launch_bounds__(256) void k_attn(
    const int* __restrict__ offsets, const float* __restrict__ sein,
    const float* __restrict__ qk, const float* __restrict__ Wv,
    float* __restrict__ agg)
{
    __shared__ float sWv[E_IN_DIM * HID];
    int tid = threadIdx.x;
    for (int i = tid; i < E_IN_DIM * HID; i += 256) sWv[i] = Wv[i];
    __syncthreads();

    int w = tid >> 6, l = tid & 63;
    int es = l >> 3, h = l & 7;
    int n = blockIdx.x * 4 + w;
    if (n >= N_NODES) return;

    const float4* qr = (const float4*)(qk + n * 96 + h * 12);
    float4 q0 = qr[0], q1 = qr[1], q2 = qr[2];

    int beg = offsets[n];
    int cnt = offsets[n + 1] - beg;
    const float* base = sein + (size_t)beg * 12;

    float sr[12];
    #pragma unroll
    for (int j = 0; j < 12; ++j) sr[j] = 0.f;
    float denom = 0.f;

    for (int r0 = 0; r0 < cnt; r0 += 32) {
        #pragma unroll
        for (int u = 0; u < 4; ++u) {
            int r = r0 + u * 8 + es;
            bool act = r < cnt;
            int rc = act ? r : (cnt - 1);
            const float4* p = (const float4*)(base + (size_t)rc * 12);
            float4 x0 = p[0], x1 = p[1], ea = p[2];
            float sc = x0.x*q0.x + x0.y*q0.y + x0.z*q0.z + x0.w*q0.w
                     + x1.x*q1.x + x1.y*q1.y + x1.z*q1.z + x1.w*q1.w
                     + ea.x*q2.x + ea.y*q2.y + ea.z*q2.z + ea.w*q2.w;
            float ex = act ? __expf(sc) : 0.f;
            denom += ex;
            sr[0] += ex * x0.x; sr[1]  += ex * x0.y; sr[2]  += ex * x0.z; sr[3]  += ex * x0.w;
            sr[4] += ex * x1.x; sr[5]  += ex * x1.y; sr[6]  += ex * x1.z; sr[7]  += ex * x1.w;
            sr[8] += ex * ea.x; sr[9]  += ex * ea.y; sr[10] += ex * ea.z; sr[11] += ex * ea.w;
        }
    }

    #pragma unroll
    for (int m = 8; m <= 32; m <<= 1) {
        denom += __shfl_xor(denom, m);
        #pragma unroll
        for (int j = 0; j < 12; ++j) sr[j] += __shfl_xor(sr[j], m);
    }

    float inv = 1.0f / fmaxf(denom, 1e-9f);
    int d0 = h * DH + 2 * es;
    float a0 = 0.f, a1 = 0.f;
    #pragma unroll
    for (int j = 0; j < E_IN_DIM; ++j) {
        a0 += sr[j] * sWv[j * HID + d0];
        a1 += sr[j] * sWv[j * HID + d0 + 1];
    }
    *(float2*)(agg + (size_t)n * HID + d0) = make_float2(a0 * inv, a1 * inv);
}

// ---------------- MLP: LDS-tiled feats = agg@Wo, relu, @lin_W, pool (LDS-bucketed atomics).
__global__ __launch_bounds__(256) void k_mlp(
    const float* __restrict__ agg, const float* __restrict__ Wo,
    const float* __restrict__ lin_W, const float* __restrict__ lin_b,
    const int* __restrict__ batch,
    float* __restrict__ gsum, float* __restrict__ gcnt)
{
    __shared__ float sWo[64 * HID];
    __shared__ float sAgg[32][HID + 1];
    __shared__ float sRed[8][33];
    __shared__ float bsum[GRAPHS];
    __shared__ int   bcnt[GRAPHS];

    int tid = threadIdx.x;
    int nbase = blockIdx.x * 32;

    if (tid < GRAPHS) { bsum[tid] = 0.f; bcnt[tid] = 0; }

    {
        const float4* ag = (const float4*)(agg + (size_t)nbase * HID);
        #pragma unroll
        for (int k = 0; k < 4; ++k) {
            int i4 = k * 256 + tid;
            float4 v = ag[i4];
            int fi = i4 * 4;
            int r = fi >> 7, c = fi & 127;
            sAgg[r][c] = v.x; sAgg[r][c + 1] = v.y; sAgg[r][c + 2] = v.z; sAgg[r][c + 3] = v.w;
        }
    }

    int h  = tid >> 5;
    int nl = tid & 31;
    int n  = nbase + nl;

    float f[16];
    #pragma unroll
    for (int d = 0; d < 16; ++d) f[d] = 0.f;

    #pragma unroll
    for (int half = 0; half < 2; ++half) {
        __syncthreads();
        const float4* wp = (const float4*)(Wo + half * 64 * HID);
        #pragma unroll
        for (int k = 0; k < 8; ++k) {
            int i4 = k * 256 + tid;
            ((float4*)sWo)[i4] = wp[i4];
        }
        __syncthreads();
        #pragma unroll 4
        for (int i = 0; i < 64; ++i) {
            float av = sAgg[nl][half * 64 + i];
            const float4* wr = (const float4*)(sWo + i * HID + h * 16);
            float4 w0 = wr[0], w1 = wr[1], w2 = wr[2], w3 = wr[3];
            f[0]  += av * w0.x; f[1]  += av * w0.y; f[2]  += av * w0.z; f[3]  += av * w0.w;
            f[4]  += av * w1.x; f[5]  += av * w1.y; f[6]  += av * w1.z; f[7]  += av * w1.w;
            f[8]  += av * w2.x; f[9]  += av * w2.y; f[10] += av * w2.z; f[11] += av * w2.w;
            f[12] += av * w3.x; f[13] += av * w3.y; f[14] += av * w3.z; f[15] += av * w3.w;
        }
    }

    const float4* lwp = (const float4*)(lin_W + h * 16);
    float4 lw0 = lwp[0], lw1 = lwp[1], lw2 = lwp[2], lw3 = lwp[3];
    float ps = fmaxf(f[0],0.f)*lw0.x + fmaxf(f[1],0.f)*lw0.y + fmaxf(f[2],0.f)*lw0.z + fmaxf(f[3],0.f)*lw0.w
             + fmaxf(f[4],0.f)*lw1.x + fmaxf(f[5],0.f)*lw1.y + fmaxf(f[6],0.f)*lw1.z + fmaxf(f[7],0.f)*lw1.w
             + fmaxf(f[8],0.f)*lw2.x + fmaxf(f[9],0.f)*lw2.y + fmaxf(f[10],0.f)*lw2.z + fmaxf(f[11],0.f)*lw2.w
             + fmaxf(f[12],0.f)*lw3.x + fmaxf(f[13],0.f)*lw3.y + fmaxf(f[14],0.f)*lw3.z + fmaxf(f[15],0.f)*lw3.w;

    sRed[h][nl] = ps;
    __syncthreads();
    if (h == 0 && n < N_NODES) {
        float y = lin_b[0];
        #pragma unroll
        for (int k = 0; k < 8; ++k) y += sRed[k][nl];
        int g = batch[n];
        atomicAdd(&bsum[g], y);
        atomicAdd(&bcnt[g], 1);
    }
    __syncthreads();
    if (tid < GRAPHS) {
        int c = bcnt[tid];
        if (c > 0) {
            atomicAdd(&gsum[tid], bsum[tid]);
            atomicAdd(&gcnt[tid], (float)c);
        }
    }
}

__global__ void k_final(const float* __restrict__ gsum, const float* __restrict__ gcnt,
                        float* __restrict__ out)
{
    int g = threadIdx.x;
    if (g < GRAPHS) out[g] = gsum[g] / fmaxf(gcnt[g], 1.0f);
}

extern "C" void kernel_launch(void* const* d_in, const int* in_sizes, int n_in,
                              void* d_out, int out_size, void* d_ws, size_t ws_size,
                              hipStream_t stream)
{
    const float* pos       = (const float*)d_in[0];
    const int*   z         = (const int*)  d_in[1];
    const int*   edge_index= (const int*)  d_in[2];
    const float* edge_attr = (const float*)d_in[3];
    const int*   batch     = (const int*)  d_in[4];
    const float* emb       = (const float*)d_in[5];
    const float* Wq        = (const float*)d_in[6];
    const float* Wk        = (const float*)d_in[7];
    const float* Wv        = (const float*)d_in[8];
    const float* Wo        = (const float*)d_in[9];
    const float* lin_W     = (const float*)d_in[10];
    const float* lin_b     = (const float*)d_in[11];
    float* out = (float*)d_out;

    char* ws = (char*)d_ws;
    int*   counts  = (int*)ws;                    // 50000
    float* gsum    = (float*)(counts + N_NODES);  // 64
    float* gcnt    = gsum + GRAPHS;               // 64
    int*   offsets = (int*)(gcnt + GRAPHS);       // 50004
    int*   woff    = offsets + 50004;             // 50000
    int*   bsum    = woff + N_NODES;              // 196
    int*   bbase   = bsum + NSCB;                 // 204 (pad to keep 16B)
    char*  tail    = (char*)(bbase + 204);
    size_t fixed   = (size_t)(tail - ws);

    size_t need_main = fixed + (size_t)N_EDGES * 48          // sein
                     + (size_t)N_NODES * 32                  // x
                     + (size_t)N_NODES * 384                 // qk
                     + (size_t)N_PAD   * 512;                // agg (padded)

    hipMemsetAsync(counts, 0, (size_t)(N_NODES + 2 * GRAPHS) * sizeof(int), stream);

    float* sein = (float*)tail;
    float* x    = sein + (size_t)N_EDGES * 12;
    float* qk   = x + (size_t)N_NODES * 8;
    float* agg  = qk + (size_t)N_NODES * 96;
    (void)need_main; (void)ws_size;

    k_node1      <<<(N_NODES + 31) / 32, 256, 0, stream>>>(pos, z, emb, Wq, Wk, x, qk);
    k_hist       <<<(N_EDGES / 4 + 255) / 256, 256, 0, stream>>>(edge_index, counts);
    k_scan1      <<<NSCB, 256, 0, stream>>>(counts, offsets, bsum);
    k_scan2      <<<1, 256, 0, stream>>>(bsum, bbase, offsets);
    k_scan3      <<<NSCB, 256, 0, stream>>>(offsets, woff, bbase);
    k_scatter_ein<<<(N_EDGES + 255) / 256, 256, 0, stream>>>(edge_index, edge_attr, x, woff, sein);
    k_attn       <<<(N_NODES + 3) / 4, 256, 0, stream>>>(offsets, sein, qk, Wv, agg);
    k_mlp        <<<(N_PAD / 32), 256, 0, stream>>>(agg, Wo, lin_W, lin_b, batch, gsum, gcnt);
    k_final      <<<1, 64, 0, stream>>>(gsum, gcnt, out);
}